// Round 8
// baseline (252.223 us; speedup 1.0000x reference)
//
#include <hip/hip_runtime.h>

#define D_IN  128
#define D_OUT 32
#define H     512
#define W     512
#define W4    128               // W/4 float4 lanes per row
#define POS   (H * W4)          // float4 per input slice
#define HB    16                // output H rows per block
#define ZR    (HB + 8)          // rows incl. h-halo (24)
#define NTHR  512
#define NPOS  6                 // ZR*W4 / NTHR positions per thread
#define CONV_GRID (D_OUT * (H / HB))   // 32 * 32 = 1024 blocks

// v9 = v4 + cross-batch software pipeline. v8's null result (traffic -30%,
// time unchanged) falsified the traffic model: the conv is duty-cycle bound --
// each 9-load batch fully drained before the next issued (sched_barrier
// between issue and FMA stopped cross-batch issue). Here batches double-buffer
// through A/B register sets: batch j+1 is ISSUED before batch j is consumed,
// so ~9 wave-loads stay in flight continuously (auto s_waitcnt vmcnt(9) waits
// only for the consumed batch). Boundary rows are clamp+mask (wave-uniform
// rowOk applied at the zbuf store) to keep the pipeline branch-free.
__global__ __launch_bounds__(NTHR)
void conv3d_fused(const float* __restrict__ inp, float* __restrict__ out,
                  const float* __restrict__ bxy_p, const float* __restrict__ bz_p,
                  float* __restrict__ blkMin, float* __restrict__ blkMax) {
    __shared__ float zbuf[ZR * W];   // 48 KiB
    __shared__ float smin[8], smax[8];

    const int tid = threadIdx.x;
    const int d  = blockIdx.x >> 5;        // 0..31
    const int h0 = (blockIdx.x & 31) * HB;

    const float bz = bz_p[0], bx = bxy_p[0];
    const float iz = 1.0f / (2.0f * bz * bz);
    const float ix = 1.0f / (2.0f * bx * bx);
    float wz[9], wx[9];
#pragma unroll
    for (int k = 0; k < 9; ++k) {
        float dd = (float)(k - 4);
        wz[k] = expf(-dd * dd * iz);
        wx[k] = expf(-dd * dd * ix);
    }

    const float4* in4 = (const float4*)inp;
    float4* z4 = (float4*)zbuf;
    const float4 f4z = make_float4(0.f, 0.f, 0.f, 0.f);

#define FMA4(A, V, Wc) do { (A).x += (V).x * (Wc); (A).y += (V).y * (Wc); \
                            (A).z += (V).z * (Wc); (A).w += (V).w * (Wc); } while (0)

    // per-thread tile positions; r = pos>>7 wave-uniform -> rowOk wave-uniform
    int  rowOffC[NPOS];   // h clamped to [0,H-1] -> always-valid address
    bool rowOk[NPOS];
#pragma unroll
    for (int j = 0; j < NPOS; ++j) {
        int pos = j * NTHR + tid;
        int r   = pos >> 7;
        int c4  = pos & (W4 - 1);
        int h   = h0 - 4 + r;
        rowOk[j]   = (unsigned)h < H;
        int hc     = h < 0 ? 0 : (h > H - 1 ? H - 1 : h);
        rowOffC[j] = hc * W4 + c4;
    }

    const int dinBase = 4 * d - 3;
    const bool interior = (d >= 1) && (d <= 30);   // all 9 z-taps in range

    if (interior) {
        const float4* base = in4 + (ptrdiff_t)dinBase * POS;
        float4 A[9], B[9];

        auto issue = [&](int j, float4 (&buf)[9]) {
            const float4* p = base + rowOffC[j];
#pragma unroll
            for (int s = 0; s < 9; ++s) buf[s] = p[s * POS];
        };
        auto consume = [&](int j, float4 (&buf)[9]) {
            float4 a0 = f4z;
#pragma unroll
            for (int s = 0; s < 9; ++s) FMA4(a0, buf[s], wz[s]);
            z4[j * NTHR + tid] = rowOk[j] ? a0 : f4z;
        };

        issue(0, A);
#pragma unroll
        for (int j = 0; j < NPOS; ++j) {       // j compile-time (full unroll)
            if (j + 1 < NPOS) {
                if ((j & 1) == 0) issue(j + 1, B);
                else              issue(j + 1, A);
            }
            __builtin_amdgcn_sched_barrier(0);  // pin issue above consumption
            if ((j & 1) == 0) consume(j, A);
            else              consume(j, B);
        }
    } else {
        // edge d: per-tap wave-uniform z guard, no pipeline (2/32 blocks)
#pragma unroll
        for (int j = 0; j < NPOS; ++j) {
            float4 a0 = f4z;
#pragma unroll
            for (int s = 0; s < 9; ++s) {
                int z = dinBase + s;
                if ((unsigned)z < D_IN) {
                    float4 v = in4[(size_t)z * POS + rowOffC[j]];
                    FMA4(a0, v, wz[s]);
                }
            }
            z4[j * NTHR + tid] = rowOk[j] ? a0 : f4z;
        }
    }
    __syncthreads();

    // ---- fused h-conv + w-conv (v4-proven), block min/max ----
    const int lane = tid & 63;
    float lmin =  3.402823466e38f;
    float lmax = -3.402823466e38f;
    float4* out4 = (float4*)out;

    for (int t = tid; t < HB * W4; t += NTHR) {   // 4 iterations
        int r  = t >> 7;            // wave-uniform
        int c4 = t & (W4 - 1);      // consecutive across lanes

        // h-conv at (r, c4)
        float4 v = f4z;
#pragma unroll
        for (int k = 0; k < 9; ++k) {
            float4 z = z4[(r + k) * W4 + c4];
            FMA4(v, z, wx[k]);
        }

        // w-neighbors from adjacent lanes
        float4 va, vc;
        va.x = __shfl_up(v.x, 1, 64);   va.y = __shfl_up(v.y, 1, 64);
        va.z = __shfl_up(v.z, 1, 64);   va.w = __shfl_up(v.w, 1, 64);
        vc.x = __shfl_down(v.x, 1, 64); vc.y = __shfl_down(v.y, 1, 64);
        vc.z = __shfl_down(v.z, 1, 64); vc.w = __shfl_down(v.w, 1, 64);

        // wave-edge lanes recompute neighbor column (OOB -> zero = w pad)
        if (lane == 0 || lane == 63) {
            int c4n = c4 + ((lane == 0) ? -1 : 1);
            float4 vn = f4z;
            if ((unsigned)c4n < W4) {
#pragma unroll
                for (int k = 0; k < 9; ++k) {
                    float4 z = z4[(r + k) * W4 + c4n];
                    FMA4(vn, z, wx[k]);
                }
            }
            if (lane == 0) va = vn; else vc = vn;
        }

        float win[12] = {va.x, va.y, va.z, va.w,
                         v.x,  v.y,  v.z,  v.w,
                         vc.x, vc.y, vc.z, vc.w};
        float4 o = f4z;
#pragma unroll
        for (int k = 0; k < 9; ++k) {
            o.x += win[k]     * wx[k];
            o.y += win[k + 1] * wx[k];
            o.z += win[k + 2] * wx[k];
            o.w += win[k + 3] * wx[k];
        }
        out4[((size_t)d * H + h0 + r) * W4 + c4] = o;
        lmin = fminf(lmin, fminf(fminf(o.x, o.y), fminf(o.z, o.w)));
        lmax = fmaxf(lmax, fmaxf(fmaxf(o.x, o.y), fmaxf(o.z, o.w)));
    }

    // ---- block min/max reduction (8 waves) ----
#pragma unroll
    for (int off = 32; off > 0; off >>= 1) {
        lmin = fminf(lmin, __shfl_down(lmin, off, 64));
        lmax = fmaxf(lmax, __shfl_down(lmax, off, 64));
    }
    int wv = tid >> 6;  // 0..7
    if (lane == 0) { smin[wv] = lmin; smax[wv] = lmax; }
    __syncthreads();
    if (tid == 0) {
        float mn = smin[0], mx = smax[0];
#pragma unroll
        for (int i = 1; i < 8; ++i) { mn = fminf(mn, smin[i]); mx = fmaxf(mx, smax[i]); }
        blkMin[blockIdx.x] = mn;
        blkMax[blockIdx.x] = mx;
    }
#undef FMA4
}

// Normalize; each block reduces the per-block min/max arrays itself
// (L2-hot, fully parallel) -> no serialized single-block reduce kernel.
#define NORM_NTHR  256
#define NORM_F4_PER_THR 4
#define NORM_GRID  ((D_OUT * H * W4) / (NORM_NTHR * NORM_F4_PER_THR))  // 2048

__global__ __launch_bounds__(NORM_NTHR)
void norm_kernel(const float* __restrict__ in, float* __restrict__ out,
                 const float* __restrict__ blkMin, const float* __restrict__ blkMax) {
    float lmin =  3.402823466e38f;
    float lmax = -3.402823466e38f;
    for (int i = threadIdx.x; i < CONV_GRID; i += NORM_NTHR) {   // 4 iterations
        lmin = fminf(lmin, blkMin[i]);
        lmax = fmaxf(lmax, blkMax[i]);
    }
#pragma unroll
    for (int off = 32; off > 0; off >>= 1) {
        lmin = fminf(lmin, __shfl_down(lmin, off, 64));
        lmax = fmaxf(lmax, __shfl_down(lmax, off, 64));
    }
    __shared__ float smin[4], smax[4];
    int lane = threadIdx.x & 63, wv = threadIdx.x >> 6;
    if (lane == 0) { smin[wv] = lmin; smax[wv] = lmax; }
    __syncthreads();
    float mn  = fminf(fminf(smin[0], smin[1]), fminf(smin[2], smin[3]));
    float mx  = fmaxf(fmaxf(smax[0], smax[1]), fmaxf(smax[2], smax[3]));
    float inv = 1.0f / (mx - mn);

    const float4* in4  = (const float4*)in;
    float4*       out4 = (float4*)out;
    int base = blockIdx.x * (NORM_NTHR * NORM_F4_PER_THR) + threadIdx.x;
#pragma unroll
    for (int j = 0; j < NORM_F4_PER_THR; ++j) {
        int idx = base + j * NORM_NTHR;
        float4 v = in4[idx];
        out4[idx] = make_float4((v.x - mn) * inv, (v.y - mn) * inv,
                                (v.z - mn) * inv, (v.w - mn) * inv);
    }
}

extern "C" void kernel_launch(void* const* d_in, const int* in_sizes, int n_in,
                              void* d_out, int out_size, void* d_ws, size_t ws_size,
                              hipStream_t stream) {
    const float* inp    = (const float*)d_in[0];
    // mu_z / sig_z only produce a positive global scale, which cancels in the
    // min-max normalization -> unused.
    const float* bet_xy = (const float*)d_in[3];
    const float* bet_z  = (const float*)d_in[4];
    float* out = (float*)d_out;

    char* ws = (char*)d_ws;
    float* blkMin = (float*)(ws + 4096);         // 1024 floats
    float* blkMax = (float*)(ws + 8192);         // 1024 floats
    float* bufA   = (float*)(ws + 65536);        // 32 MiB conv output

    conv3d_fused<<<CONV_GRID, NTHR, 0, stream>>>(inp, bufA, bet_xy, bet_z, blkMin, blkMax);
    norm_kernel<<<NORM_GRID, NORM_NTHR, 0, stream>>>(bufA, out, blkMin, blkMax);
}